// Round 13
// baseline (373.748 us; speedup 1.0000x reference)
//
#include <hip/hip_runtime.h>
#include <hip/hip_fp16.h>

constexpr int HEADS = 4;

typedef _Float16 half8 __attribute__((ext_vector_type(8)));
typedef float f32x4 __attribute__((ext_vector_type(4)));

__device__ __forceinline__ float lrelu(float x) { return x > 0.f ? x : 0.2f * x; }

// ---------------- CSR build (edges grouped by dst; reused by all 3 layers) ----------------

__global__ void count_deg_kernel(const int* __restrict__ ei, int* __restrict__ deg,
                                 int E, int N) {
  int e = blockIdx.x * 256 + threadIdx.x;
  int EP = E + N;
  if (e < EP) {
    int d = (e < E) ? ei[E + e] : (e - E);   // self-loop tail
    atomicAdd(&deg[d], 1);
  }
}

__global__ void scan_block_kernel(const int* __restrict__ deg, int* __restrict__ rowp,
                                  int* __restrict__ partials, int N) {
  __shared__ int sm[1024];
  int t = threadIdx.x;
  int i = blockIdx.x * 1024 + t;
  int v = (i < N) ? deg[i] : 0;
  sm[t] = v;
  __syncthreads();
  for (int off = 1; off < 1024; off <<= 1) {
    int tmp = (t >= off) ? sm[t - off] : 0;
    __syncthreads();
    sm[t] += tmp;
    __syncthreads();
  }
  if (i < N) rowp[i] = sm[t] - v;            // exclusive within block
  if (t == 1023) partials[blockIdx.x] = sm[t];
}

// single 1024-thr block LDS scan (nb <= 1024)
__global__ void scan_partials_kernel(int* partials, int nb) {
  __shared__ int sm[1024];
  int t = threadIdx.x;
  int v = (t < nb) ? partials[t] : 0;
  sm[t] = v;
  __syncthreads();
  for (int off = 1; off < 1024; off <<= 1) {
    int tmp = (t >= off) ? sm[t - off] : 0;
    __syncthreads();
    sm[t] += tmp;
    __syncthreads();
  }
  if (t < nb) partials[t] = sm[t] - v;       // exclusive
}

__global__ void add_off_kernel(int* __restrict__ rowp, const int* __restrict__ partials,
                               int N, int EP) {
  int i = blockIdx.x * 256 + threadIdx.x;
  if (i < N) rowp[i] += partials[i >> 10];
  if (i == 0) rowp[N] = EP;
}

__global__ void scatter_kernel(const int* __restrict__ ei, const int* __restrict__ rowp,
                               int* __restrict__ cursor, int* __restrict__ col,
                               int E, int N) {
  int e = blockIdx.x * 256 + threadIdx.x;
  int EP = E + N;
  if (e < EP) {
    int s, d;
    if (e < E) { s = ei[e]; d = ei[E + e]; }
    else       { s = e - E; d = e - E; }
    int pos = rowp[d] + atomicAdd(&cursor[d], 1);
    col[pos] = s;
  }
}

// ---------------- weight transpose+convert: W [128,Fout] fp32 -> Wt [Fout,128] fp16 ----

__global__ void convert_wt3_kernel(const float* __restrict__ W1, _Float16* __restrict__ Wt1,
                                   const float* __restrict__ W2, _Float16* __restrict__ Wt2,
                                   const float* __restrict__ W3, _Float16* __restrict__ Wt3) {
  const float* W; _Float16* Wt; int Fout;
  if (blockIdx.y == 0)      { W = W1; Wt = Wt1; Fout = 128; }
  else if (blockIdx.y == 1) { W = W2; Wt = Wt2; Fout = 128; }
  else                      { W = W3; Wt = Wt3; Fout = 256; }
  int i = blockIdx.x * 256 + threadIdx.x;
  if (i < 128 * Fout) {
    int c = i >> 7, k = i & 127;
    Wt[c * 128 + k] = (_Float16)W[k * Fout + c];
  }
}

// ---------------- MFMA GEMM v2: B panel staged in LDS (XOR-swizzled) + fused alpha ----

template <int AF32, int CPH>
__global__ __launch_bounds__(256) void gemm_mfma_kernel(
    const void* __restrict__ Xv, const _Float16* __restrict__ Wt,
    const float* __restrict__ a_s, const float* __restrict__ a_d,
    _Float16* __restrict__ O, float* __restrict__ asrc, float* __restrict__ adst,
    int N, int Fout) {
  __shared__ __align__(16) char Bl[32768];      // 128 cols x 128 k x 2B
  const int t = threadIdx.x;
  const int w = t >> 6;
  const int lane = t & 63;
  const int r = lane & 15, g = lane >> 4;
  const int row0 = blockIdx.x * 64 + w * 16;
  const int colpan = blockIdx.y * 128;

#pragma unroll
  for (int i = 0; i < 8; ++i) {
    int lin = i * 256 + t;                      // 16B chunk id
    int c0 = lin >> 4;                          // col 0..127
    int kb = lin & 15;                          // 16B chunk along k
    half8 v = *(const half8*)&Wt[(size_t)(colpan + c0) * 128 + kb * 8];
    int addr = (c0 * 256 + kb * 16) ^ ((c0 & 7) << 4);
    *(half8*)(Bl + addr) = v;
  }
  __syncthreads();

  int rowl = row0 + r;
  if (rowl >= N) rowl = N - 1;                  // clamp for loads; stores guarded

  f32x4 acc[8];
#pragma unroll
  for (int c = 0; c < 8; ++c) acc[c] = {0.f, 0.f, 0.f, 0.f};

#pragma unroll
  for (int s = 0; s < 4; ++s) {
    half8 a;
    if constexpr (AF32) {
      const float* X = (const float*)Xv;
      float4 a0 = *(const float4*)&X[(size_t)rowl * 128 + s * 32 + g * 8];
      float4 a1 = *(const float4*)&X[(size_t)rowl * 128 + s * 32 + g * 8 + 4];
      a = half8{(_Float16)a0.x, (_Float16)a0.y, (_Float16)a0.z, (_Float16)a0.w,
                (_Float16)a1.x, (_Float16)a1.y, (_Float16)a1.z, (_Float16)a1.w};
    } else {
      const _Float16* X = (const _Float16*)Xv;
      a = *(const half8*)&X[(size_t)rowl * 128 + s * 32 + g * 8];
    }
#pragma unroll
    for (int c = 0; c < 8; ++c) {
      int colr = c * 16 + r;
      int addr = (colr * 256 + s * 64 + g * 16) ^ ((colr & 7) << 4);
      half8 b = *(const half8*)(Bl + addr);
      acc[c] = __builtin_amdgcn_mfma_f32_16x16x32_f16(a, b, acc[c], 0, 0, 0);
    }
  }

#pragma unroll
  for (int c = 0; c < 8; ++c) {
    int ocol = colpan + c * 16 + r;
#pragma unroll
    for (int q = 0; q < 4; ++q) {
      int orow = row0 + g * 4 + q;
      if (orow < N) O[(size_t)orow * Fout + ocol] = (_Float16)acc[c][q];
    }
  }

  constexpr int HPP = 8 / CPH;          // heads in this panel
  constexpr int C = CPH * 16;           // channels per head
  const int hbase = blockIdx.y * HPP;
  float ps[4][HPP], pd[4][HPP];
#pragma unroll
  for (int q = 0; q < 4; ++q)
#pragma unroll
    for (int hh = 0; hh < HPP; ++hh) { ps[q][hh] = 0.f; pd[q][hh] = 0.f; }

#pragma unroll
  for (int c = 0; c < 8; ++c) {
    int hh = c / CPH;
    int ch = (c % CPH) * 16 + r;
    float asv = a_s[(hbase + hh) * C + ch];
    float adv = a_d[(hbase + hh) * C + ch];
#pragma unroll
    for (int q = 0; q < 4; ++q) {
      ps[q][hh] += acc[c][q] * asv;
      pd[q][hh] += acc[c][q] * adv;
    }
  }
#pragma unroll
  for (int m = 1; m < 16; m <<= 1) {
#pragma unroll
    for (int q = 0; q < 4; ++q)
#pragma unroll
      for (int hh = 0; hh < HPP; ++hh) {
        ps[q][hh] += __shfl_xor(ps[q][hh], m, 64);
        pd[q][hh] += __shfl_xor(pd[q][hh], m, 64);
      }
  }
  if (r == 0) {
#pragma unroll
    for (int q = 0; q < 4; ++q) {
      int row = row0 + g * 4 + q;
      if (row < N) {
#pragma unroll
        for (int hh = 0; hh < HPP; ++hh) {
          asrc[row * 4 + hbase + hh] = ps[q][hh];
          adst[row * 4 + hbase + hh] = pd[q][hh];
        }
      }
    }
  }
}

// ---------------- aggregation v4: 16B gathers, deeper MLP ----------------
// concat: 4 waves/block = 4 nodes; wave = 4 edge-groups x 16 lanes; lane = half8.
// Main loop 16 edges/iter (4/group), then 8, then masked 4-step tail.

__global__ __launch_bounds__(256) void aggregate_concat_kernel(
    const _Float16* __restrict__ H, const float* __restrict__ asrc,
    const float* __restrict__ adst, const float* __restrict__ bias,
    const int* __restrict__ rowp, const int* __restrict__ col,
    _Float16* __restrict__ out, int N) {
  int n = blockIdx.x * 4 + (threadIdx.x >> 6);
  if (n >= N) return;
  int lane = threadIdx.x & 63;
  int g = lane >> 4;               // edge group 0..3
  int l16 = lane & 15;             // 16B slot in row
  int h = l16 >> 2;                // head
  float ad = adst[n * 4 + h];
  int j = rowp[n], end = rowp[n + 1];
  float acc[8] = {};
  float denom = 0.f;
  for (; j + 16 <= end; j += 16) { // 16 edges per iter: 4 per group
    int s0 = col[j + g];
    int s1 = col[j + 4 + g];
    int s2 = col[j + 8 + g];
    int s3 = col[j + 12 + g];
    float w0 = __expf(lrelu(asrc[s0 * 4 + h] + ad));
    float w1 = __expf(lrelu(asrc[s1 * 4 + h] + ad));
    float w2 = __expf(lrelu(asrc[s2 * 4 + h] + ad));
    float w3 = __expf(lrelu(asrc[s3 * 4 + h] + ad));
    half8 f0 = *(const half8*)&H[(size_t)s0 * 128 + l16 * 8];
    half8 f1 = *(const half8*)&H[(size_t)s1 * 128 + l16 * 8];
    half8 f2 = *(const half8*)&H[(size_t)s2 * 128 + l16 * 8];
    half8 f3 = *(const half8*)&H[(size_t)s3 * 128 + l16 * 8];
    denom += (w0 + w1) + (w2 + w3);
#pragma unroll
    for (int c = 0; c < 8; ++c)
      acc[c] += (w0 * (float)f0[c] + w1 * (float)f1[c]) +
                (w2 * (float)f2[c] + w3 * (float)f3[c]);
  }
  if (j + 8 <= end) {              // 8 edges: 2 per group
    int s0 = col[j + g];
    int s1 = col[j + 4 + g];
    float w0 = __expf(lrelu(asrc[s0 * 4 + h] + ad));
    float w1 = __expf(lrelu(asrc[s1 * 4 + h] + ad));
    half8 f0 = *(const half8*)&H[(size_t)s0 * 128 + l16 * 8];
    half8 f1 = *(const half8*)&H[(size_t)s1 * 128 + l16 * 8];
    denom += w0 + w1;
#pragma unroll
    for (int c = 0; c < 8; ++c) acc[c] += w0 * (float)f0[c] + w1 * (float)f1[c];
    j += 8;
  }
  for (int base = j; base < end; base += 4) {   // tail: exec-masked
    int idx = base + g;
    if (idx < end) {
      int s0 = col[idx];
      float w0 = __expf(lrelu(asrc[s0 * 4 + h] + ad));
      half8 f0 = *(const half8*)&H[(size_t)s0 * 128 + l16 * 8];
      denom += w0;
#pragma unroll
      for (int c = 0; c < 8; ++c) acc[c] += w0 * (float)f0[c];
    }
  }
#pragma unroll
  for (int m = 16; m <= 32; m <<= 1) {
    denom += __shfl_xor(denom, m, 64);
#pragma unroll
    for (int c = 0; c < 8; ++c) acc[c] += __shfl_xor(acc[c], m, 64);
  }
  if (g == 0) {
    float inv = 1.f / denom;
    float4 b0 = *(const float4*)&bias[l16 * 8];
    float4 b1 = *(const float4*)&bias[l16 * 8 + 4];
    half8 o;
    o[0] = (_Float16)(acc[0] * inv + b0.x); o[1] = (_Float16)(acc[1] * inv + b0.y);
    o[2] = (_Float16)(acc[2] * inv + b0.z); o[3] = (_Float16)(acc[3] * inv + b0.w);
    o[4] = (_Float16)(acc[4] * inv + b1.x); o[5] = (_Float16)(acc[5] * inv + b1.y);
    o[6] = (_Float16)(acc[6] * inv + b1.z); o[7] = (_Float16)(acc[7] * inv + b1.w);
    *(half8*)&out[(size_t)n * 128 + l16 * 8] = o;
  }
}

// layer 3: rows 512B. 2 waves/block = 2 nodes; wave = 2 edge-groups x 32 lanes.
// Main loop 8 edges/iter (4/group), then 4, then masked 2-step tail.

__global__ __launch_bounds__(128) void aggregate_mean_kernel(
    const _Float16* __restrict__ H, const float* __restrict__ asrc,
    const float* __restrict__ adst, const float* __restrict__ bias,
    const int* __restrict__ rowp, const int* __restrict__ col,
    float* __restrict__ out, int N) {
  int n = blockIdx.x * 2 + (threadIdx.x >> 6);
  if (n >= N) return;
  int lane = threadIdx.x & 63;
  int g = lane >> 5;               // edge group 0..1
  int l32 = lane & 31;             // 16B slot in row
  int h = l32 >> 3;                // head
  float ad = adst[n * 4 + h];
  int j = rowp[n], end = rowp[n + 1];
  float acc[8] = {};
  float denom = 0.f;
  for (; j + 8 <= end; j += 8) {   // 8 edges per iter: 4 per group
    int s0 = col[j + g];
    int s1 = col[j + 2 + g];
    int s2 = col[j + 4 + g];
    int s3 = col[j + 6 + g];
    float w0 = __expf(lrelu(asrc[s0 * 4 + h] + ad));
    float w1 = __expf(lrelu(asrc[s1 * 4 + h] + ad));
    float w2 = __expf(lrelu(asrc[s2 * 4 + h] + ad));
    float w3 = __expf(lrelu(asrc[s3 * 4 + h] + ad));
    half8 f0 = *(const half8*)&H[(size_t)s0 * 256 + l32 * 8];
    half8 f1 = *(const half8*)&H[(size_t)s1 * 256 + l32 * 8];
    half8 f2 = *(const half8*)&H[(size_t)s2 * 256 + l32 * 8];
    half8 f3 = *(const half8*)&H[(size_t)s3 * 256 + l32 * 8];
    denom += (w0 + w1) + (w2 + w3);
#pragma unroll
    for (int c = 0; c < 8; ++c)
      acc[c] += (w0 * (float)f0[c] + w1 * (float)f1[c]) +
                (w2 * (float)f2[c] + w3 * (float)f3[c]);
  }
  if (j + 4 <= end) {              // 4 edges: 2 per group
    int s0 = col[j + g];
    int s1 = col[j + 2 + g];
    float w0 = __expf(lrelu(asrc[s0 * 4 + h] + ad));
    float w1 = __expf(lrelu(asrc[s1 * 4 + h] + ad));
    half8 f0 = *(const half8*)&H[(size_t)s0 * 256 + l32 * 8];
    half8 f1 = *(const half8*)&H[(size_t)s1 * 256 + l32 * 8];
    denom += w0 + w1;
#pragma unroll
    for (int c = 0; c < 8; ++c) acc[c] += w0 * (float)f0[c] + w1 * (float)f1[c];
    j += 4;
  }
  for (int base = j; base < end; base += 2) {   // tail: exec-masked
    int idx = base + g;
    if (idx < end) {
      int s0 = col[idx];
      float w0 = __expf(lrelu(asrc[s0 * 4 + h] + ad));
      half8 f0 = *(const half8*)&H[(size_t)s0 * 256 + l32 * 8];
      denom += w0;
#pragma unroll
      for (int c = 0; c < 8; ++c) acc[c] += w0 * (float)f0[c];
    }
  }
  denom += __shfl_xor(denom, 32, 64);
#pragma unroll
  for (int c = 0; c < 8; ++c) acc[c] += __shfl_xor(acc[c], 32, 64);
  float inv = 0.25f / denom;
#pragma unroll
  for (int c = 0; c < 8; ++c) acc[c] *= inv;
#pragma unroll
  for (int m = 8; m <= 16; m <<= 1) {
#pragma unroll
    for (int c = 0; c < 8; ++c) acc[c] += __shfl_xor(acc[c], m, 64);
  }
  if (lane < 8) {
    int cb = lane * 8;
    float4 b0 = *(const float4*)&bias[cb];
    float4 b1 = *(const float4*)&bias[cb + 4];
    float4 o0 = make_float4(acc[0] + b0.x, acc[1] + b0.y, acc[2] + b0.z, acc[3] + b0.w);
    float4 o1 = make_float4(acc[4] + b1.x, acc[5] + b1.y, acc[6] + b1.z, acc[7] + b1.w);
    *(float4*)&out[(size_t)n * 64 + cb] = o0;
    *(float4*)&out[(size_t)n * 64 + cb + 4] = o1;
  }
}

// ---------------- host launch ----------------

extern "C" void kernel_launch(void* const* d_in, const int* in_sizes, int n_in,
                              void* d_out, int out_size, void* d_ws, size_t ws_size,
                              hipStream_t stream) {
  const float* x   = (const float*)d_in[0];
  const int*   ei  = (const int*)d_in[1];
  const float* W1  = (const float*)d_in[2];
  const float* as1 = (const float*)d_in[3];
  const float* ad1 = (const float*)d_in[4];
  const float* b1  = (const float*)d_in[5];
  const float* W2  = (const float*)d_in[6];
  const float* as2 = (const float*)d_in[7];
  const float* ad2 = (const float*)d_in[8];
  const float* b2  = (const float*)d_in[9];
  const float* W3  = (const float*)d_in[10];
  const float* as3 = (const float*)d_in[11];
  const float* ad3 = (const float*)d_in[12];
  const float* b3  = (const float*)d_in[13];
  float* out = (float*)d_out;

  const int N  = in_sizes[0] / 128;
  const int E  = in_sizes[1] / 2;
  const int EP = E + N;

  char* p = (char*)d_ws;
  auto carve = [&](size_t bytes) -> void* {
    void* r = (void*)p;
    p += (bytes + 255) & ~size_t(255);
    return r;
  };
  int*      deg  = (int*)carve(size_t(N) * 4);
  int*      rowp = (int*)carve(size_t(N + 1) * 4);
  int*      cur  = (int*)carve(size_t(N) * 4);
  int*      part = (int*)carve(1024 * 4);
  int*      col  = (int*)carve(size_t(EP) * 4);
  float*    asrc = (float*)carve(size_t(N) * HEADS * 4);
  float*    adst = (float*)carve(size_t(N) * HEADS * 4);
  _Float16* Wt1  = (_Float16*)carve(128 * 128 * 2);
  _Float16* Wt2  = (_Float16*)carve(128 * 128 * 2);
  _Float16* Wt3  = (_Float16*)carve(256 * 128 * 2);
  _Float16* Hb   = (_Float16*)carve(size_t(N) * 256 * 2);  // gemm outputs
  _Float16* Ab   = (_Float16*)carve(size_t(N) * 128 * 2);  // aggregation outputs

  hipMemsetAsync(deg, 0, size_t(N) * 4, stream);
  hipMemsetAsync(cur, 0, size_t(N) * 4, stream);

  int gEP = (EP + 255) / 256;
  count_deg_kernel<<<gEP, 256, 0, stream>>>(ei, deg, E, N);
  int nb = (N + 1023) / 1024;
  scan_block_kernel<<<nb, 1024, 0, stream>>>(deg, rowp, part, N);
  scan_partials_kernel<<<1, 1024, 0, stream>>>(part, nb);
  add_off_kernel<<<(N + 256) / 256, 256, 0, stream>>>(rowp, part, N, EP);
  scatter_kernel<<<gEP, 256, 0, stream>>>(ei, rowp, cur, col, E, N);

  convert_wt3_kernel<<<dim3(128, 3), 256, 0, stream>>>(W1, Wt1, W2, Wt2, W3, Wt3);

  int gM = (N + 63) / 64;
  int gN4 = (N + 3) / 4;
  int gN2 = (N + 1) / 2;

  // layer 1 (A = x fp32 converted in-register; alpha fused into epilogue)
  gemm_mfma_kernel<1, 2><<<dim3(gM, 1), 256, 0, stream>>>(
      x, Wt1, as1, ad1, Hb, asrc, adst, N, 128);
  aggregate_concat_kernel<<<gN4, 256, 0, stream>>>(Hb, asrc, adst, b1, rowp, col, Ab, N);
  // layer 2
  gemm_mfma_kernel<0, 2><<<dim3(gM, 1), 256, 0, stream>>>(
      Ab, Wt2, as2, ad2, Hb, asrc, adst, N, 128);
  aggregate_concat_kernel<<<gN4, 256, 0, stream>>>(Hb, asrc, adst, b2, rowp, col, Ab, N);
  // layer 3 (Fout=256, C=64, two col-panels of 2 heads each; mean over heads)
  gemm_mfma_kernel<0, 4><<<dim3(gM, 2), 256, 0, stream>>>(
      Ab, Wt3, as3, ad3, Hb, asrc, adst, N, 256);
  aggregate_mean_kernel<<<gN2, 128, 0, stream>>>(Hb, asrc, adst, b3, rowp, col, out, N);
}

// Round 15
// 367.811 us; speedup vs baseline: 1.0161x; 1.0161x over previous
//
#include <hip/hip_runtime.h>
#include <hip/hip_fp16.h>

constexpr int HEADS = 4;

typedef _Float16 half8 __attribute__((ext_vector_type(8)));
typedef float f32x4 __attribute__((ext_vector_type(4)));

__device__ __forceinline__ float lrelu(float x) { return x > 0.f ? x : 0.2f * x; }

// ---------------- CSR build (edges grouped by dst; reused by all 3 layers) ----------------

__global__ void count_deg_kernel(const int* __restrict__ ei, int* __restrict__ deg,
                                 int E, int N) {
  int e = blockIdx.x * 256 + threadIdx.x;
  int EP = E + N;
  if (e < EP) {
    int d = (e < E) ? ei[E + e] : (e - E);   // self-loop tail
    atomicAdd(&deg[d], 1);
  }
}

__global__ void scan_block_kernel(const int* __restrict__ deg, int* __restrict__ rowp,
                                  int* __restrict__ partials, int N) {
  __shared__ int sm[1024];
  int t = threadIdx.x;
  int i = blockIdx.x * 1024 + t;
  int v = (i < N) ? deg[i] : 0;
  sm[t] = v;
  __syncthreads();
  for (int off = 1; off < 1024; off <<= 1) {
    int tmp = (t >= off) ? sm[t - off] : 0;
    __syncthreads();
    sm[t] += tmp;
    __syncthreads();
  }
  if (i < N) rowp[i] = sm[t] - v;            // exclusive within block
  if (t == 1023) partials[blockIdx.x] = sm[t];
}

// single 1024-thr block LDS scan (nb <= 1024)
__global__ void scan_partials_kernel(int* partials, int nb) {
  __shared__ int sm[1024];
  int t = threadIdx.x;
  int v = (t < nb) ? partials[t] : 0;
  sm[t] = v;
  __syncthreads();
  for (int off = 1; off < 1024; off <<= 1) {
    int tmp = (t >= off) ? sm[t - off] : 0;
    __syncthreads();
    sm[t] += tmp;
    __syncthreads();
  }
  if (t < nb) partials[t] = sm[t] - v;       // exclusive
}

__global__ void add_off_kernel(int* __restrict__ rowp, const int* __restrict__ partials,
                               int N, int EP) {
  int i = blockIdx.x * 256 + threadIdx.x;
  if (i < N) rowp[i] += partials[i >> 10];
  if (i == 0) rowp[N] = EP;
}

__global__ void scatter_kernel(const int* __restrict__ ei, const int* __restrict__ rowp,
                               int* __restrict__ cursor, int* __restrict__ col,
                               int E, int N) {
  int e = blockIdx.x * 256 + threadIdx.x;
  int EP = E + N;
  if (e < EP) {
    int s, d;
    if (e < E) { s = ei[e]; d = ei[E + e]; }
    else       { s = e - E; d = e - E; }
    int pos = rowp[d] + atomicAdd(&cursor[d], 1);
    col[pos] = s;
  }
}

// ---------------- weight transpose+convert: W [128,Fout] fp32 -> Wt [Fout,128] fp16 ----

__global__ void convert_wt3_kernel(const float* __restrict__ W1, _Float16* __restrict__ Wt1,
                                   const float* __restrict__ W2, _Float16* __restrict__ Wt2,
                                   const float* __restrict__ W3, _Float16* __restrict__ Wt3) {
  const float* W; _Float16* Wt; int Fout;
  if (blockIdx.y == 0)      { W = W1; Wt = Wt1; Fout = 128; }
  else if (blockIdx.y == 1) { W = W2; Wt = Wt2; Fout = 128; }
  else                      { W = W3; Wt = Wt3; Fout = 256; }
  int i = blockIdx.x * 256 + threadIdx.x;
  if (i < 128 * Fout) {
    int c = i >> 7, k = i & 127;
    Wt[c * 128 + k] = (_Float16)W[k * Fout + c];
  }
}

// ---------------- MFMA GEMM v3: LDS B panel + hoisted A loads + fused alpha ----
// All 4 A-slices loaded up front (independent addresses -> overlapped latency),
// then the 32 MFMAs run against LDS-resident B with no global stalls.

template <int AF32, int CPH>
__global__ __launch_bounds__(256) void gemm_mfma_kernel(
    const void* __restrict__ Xv, const _Float16* __restrict__ Wt,
    const float* __restrict__ a_s, const float* __restrict__ a_d,
    _Float16* __restrict__ O, float* __restrict__ asrc, float* __restrict__ adst,
    int N, int Fout) {
  __shared__ __align__(16) char Bl[32768];      // 128 cols x 128 k x 2B
  const int t = threadIdx.x;
  const int w = t >> 6;
  const int lane = t & 63;
  const int r = lane & 15, g = lane >> 4;
  const int row0 = blockIdx.x * 64 + w * 16;
  const int colpan = blockIdx.y * 128;

#pragma unroll
  for (int i = 0; i < 8; ++i) {
    int lin = i * 256 + t;                      // 16B chunk id
    int c0 = lin >> 4;                          // col 0..127
    int kb = lin & 15;                          // 16B chunk along k
    half8 v = *(const half8*)&Wt[(size_t)(colpan + c0) * 128 + kb * 8];
    int addr = (c0 * 256 + kb * 16) ^ ((c0 & 7) << 4);
    *(half8*)(Bl + addr) = v;
  }

  int rowl = row0 + r;
  if (rowl >= N) rowl = N - 1;                  // clamp for loads; stores guarded

  // hoisted A loads: issue all 4 slices before any MFMA
  half8 a[4];
  if constexpr (AF32) {
    const float* X = (const float*)Xv;
    float4 a0[4], a1[4];
#pragma unroll
    for (int s = 0; s < 4; ++s) {
      a0[s] = *(const float4*)&X[(size_t)rowl * 128 + s * 32 + g * 8];
      a1[s] = *(const float4*)&X[(size_t)rowl * 128 + s * 32 + g * 8 + 4];
    }
#pragma unroll
    for (int s = 0; s < 4; ++s)
      a[s] = half8{(_Float16)a0[s].x, (_Float16)a0[s].y, (_Float16)a0[s].z,
                   (_Float16)a0[s].w, (_Float16)a1[s].x, (_Float16)a1[s].y,
                   (_Float16)a1[s].z, (_Float16)a1[s].w};
  } else {
    const _Float16* X = (const _Float16*)Xv;
#pragma unroll
    for (int s = 0; s < 4; ++s)
      a[s] = *(const half8*)&X[(size_t)rowl * 128 + s * 32 + g * 8];
  }
  __syncthreads();

  f32x4 acc[8];
#pragma unroll
  for (int c = 0; c < 8; ++c) acc[c] = {0.f, 0.f, 0.f, 0.f};

#pragma unroll
  for (int s = 0; s < 4; ++s) {
#pragma unroll
    for (int c = 0; c < 8; ++c) {
      int colr = c * 16 + r;
      int addr = (colr * 256 + s * 64 + g * 16) ^ ((colr & 7) << 4);
      half8 b = *(const half8*)(Bl + addr);
      acc[c] = __builtin_amdgcn_mfma_f32_16x16x32_f16(a[s], b, acc[c], 0, 0, 0);
    }
  }

#pragma unroll
  for (int c = 0; c < 8; ++c) {
    int ocol = colpan + c * 16 + r;
#pragma unroll
    for (int q = 0; q < 4; ++q) {
      int orow = row0 + g * 4 + q;
      if (orow < N) O[(size_t)orow * Fout + ocol] = (_Float16)acc[c][q];
    }
  }

  constexpr int HPP = 8 / CPH;          // heads in this panel
  constexpr int C = CPH * 16;           // channels per head
  const int hbase = blockIdx.y * HPP;
  float ps[4][HPP], pd[4][HPP];
#pragma unroll
  for (int q = 0; q < 4; ++q)
#pragma unroll
    for (int hh = 0; hh < HPP; ++hh) { ps[q][hh] = 0.f; pd[q][hh] = 0.f; }

#pragma unroll
  for (int c = 0; c < 8; ++c) {
    int hh = c / CPH;
    int ch = (c % CPH) * 16 + r;
    float asv = a_s[(hbase + hh) * C + ch];
    float adv = a_d[(hbase + hh) * C + ch];
#pragma unroll
    for (int q = 0; q < 4; ++q) {
      ps[q][hh] += acc[c][q] * asv;
      pd[q][hh] += acc[c][q] * adv;
    }
  }
#pragma unroll
  for (int m = 1; m < 16; m <<= 1) {
#pragma unroll
    for (int q = 0; q < 4; ++q)
#pragma unroll
      for (int hh = 0; hh < HPP; ++hh) {
        ps[q][hh] += __shfl_xor(ps[q][hh], m, 64);
        pd[q][hh] += __shfl_xor(pd[q][hh], m, 64);
      }
  }
  if (r == 0) {
#pragma unroll
    for (int q = 0; q < 4; ++q) {
      int row = row0 + g * 4 + q;
      if (row < N) {
#pragma unroll
        for (int hh = 0; hh < HPP; ++hh) {
          asrc[row * 4 + hbase + hh] = ps[q][hh];
          adst[row * 4 + hbase + hh] = pd[q][hh];
        }
      }
    }
  }
}

// ---------------- aggregation v3 (round-11 proven): 16B gathers, lane-group MLP ----
// concat: 4 waves/block = 4 nodes. Wave = 4 edge-groups x 16 lanes; lane loads half8.

__global__ __launch_bounds__(256) void aggregate_concat_kernel(
    const _Float16* __restrict__ H, const float* __restrict__ asrc,
    const float* __restrict__ adst, const float* __restrict__ bias,
    const int* __restrict__ rowp, const int* __restrict__ col,
    _Float16* __restrict__ out, int N) {
  int n = blockIdx.x * 4 + (threadIdx.x >> 6);
  if (n >= N) return;
  int lane = threadIdx.x & 63;
  int g = lane >> 4;               // edge group 0..3
  int l16 = lane & 15;             // 16B slot in row
  int h = l16 >> 2;                // head
  float ad = adst[n * 4 + h];
  int j = rowp[n], end = rowp[n + 1];
  float acc[8] = {};
  float denom = 0.f;
  for (; j + 8 <= end; j += 8) {   // 8 edges per iter: 2 per group
    int s0 = col[j + g];
    int s1 = col[j + 4 + g];
    float w0 = __expf(lrelu(asrc[s0 * 4 + h] + ad));
    float w1 = __expf(lrelu(asrc[s1 * 4 + h] + ad));
    half8 f0 = *(const half8*)&H[(size_t)s0 * 128 + l16 * 8];
    half8 f1 = *(const half8*)&H[(size_t)s1 * 128 + l16 * 8];
    denom += w0 + w1;
#pragma unroll
    for (int c = 0; c < 8; ++c) acc[c] += w0 * (float)f0[c] + w1 * (float)f1[c];
  }
  for (int base = j; base < end; base += 4) {   // tail: exec-masked
    int idx = base + g;
    if (idx < end) {
      int s0 = col[idx];
      float w0 = __expf(lrelu(asrc[s0 * 4 + h] + ad));
      half8 f0 = *(const half8*)&H[(size_t)s0 * 128 + l16 * 8];
      denom += w0;
#pragma unroll
      for (int c = 0; c < 8; ++c) acc[c] += w0 * (float)f0[c];
    }
  }
#pragma unroll
  for (int m = 16; m <= 32; m <<= 1) {
    denom += __shfl_xor(denom, m, 64);
#pragma unroll
    for (int c = 0; c < 8; ++c) acc[c] += __shfl_xor(acc[c], m, 64);
  }
  if (g == 0) {
    float inv = 1.f / denom;
    float4 b0 = *(const float4*)&bias[l16 * 8];
    float4 b1 = *(const float4*)&bias[l16 * 8 + 4];
    half8 o;
    o[0] = (_Float16)(acc[0] * inv + b0.x); o[1] = (_Float16)(acc[1] * inv + b0.y);
    o[2] = (_Float16)(acc[2] * inv + b0.z); o[3] = (_Float16)(acc[3] * inv + b0.w);
    o[4] = (_Float16)(acc[4] * inv + b1.x); o[5] = (_Float16)(acc[5] * inv + b1.y);
    o[6] = (_Float16)(acc[6] * inv + b1.z); o[7] = (_Float16)(acc[7] * inv + b1.w);
    *(half8*)&out[(size_t)n * 128 + l16 * 8] = o;
  }
}

// layer 3: rows 512B. 2 waves/block = 2 nodes; wave = 2 edge-groups x 32 lanes.

__global__ __launch_bounds__(128) void aggregate_mean_kernel(
    const _Float16* __restrict__ H, const float* __restrict__ asrc,
    const float* __restrict__ adst, const float* __restrict__ bias,
    const int* __restrict__ rowp, const int* __restrict__ col,
    float* __restrict__ out, int N) {
  int n = blockIdx.x * 2 + (threadIdx.x >> 6);
  if (n >= N) return;
  int lane = threadIdx.x & 63;
  int g = lane >> 5;               // edge group 0..1
  int l32 = lane & 31;             // 16B slot in row
  int h = l32 >> 3;                // head
  float ad = adst[n * 4 + h];
  int j = rowp[n], end = rowp[n + 1];
  float acc[8] = {};
  float denom = 0.f;
  for (; j + 4 <= end; j += 4) {   // 4 edges per iter: 2 per group
    int s0 = col[j + g];
    int s1 = col[j + 2 + g];
    float w0 = __expf(lrelu(asrc[s0 * 4 + h] + ad));
    float w1 = __expf(lrelu(asrc[s1 * 4 + h] + ad));
    half8 f0 = *(const half8*)&H[(size_t)s0 * 256 + l32 * 8];
    half8 f1 = *(const half8*)&H[(size_t)s1 * 256 + l32 * 8];
    denom += w0 + w1;
#pragma unroll
    for (int c = 0; c < 8; ++c) acc[c] += w0 * (float)f0[c] + w1 * (float)f1[c];
  }
  for (int base = j; base < end; base += 2) {   // tail: exec-masked
    int idx = base + g;
    if (idx < end) {
      int s0 = col[idx];
      float w0 = __expf(lrelu(asrc[s0 * 4 + h] + ad));
      half8 f0 = *(const half8*)&H[(size_t)s0 * 256 + l32 * 8];
      denom += w0;
#pragma unroll
      for (int c = 0; c < 8; ++c) acc[c] += w0 * (float)f0[c];
    }
  }
  denom += __shfl_xor(denom, 32, 64);
#pragma unroll
  for (int c = 0; c < 8; ++c) acc[c] += __shfl_xor(acc[c], 32, 64);
  float inv = 0.25f / denom;
#pragma unroll
  for (int c = 0; c < 8; ++c) acc[c] *= inv;
#pragma unroll
  for (int m = 8; m <= 16; m <<= 1) {
#pragma unroll
    for (int c = 0; c < 8; ++c) acc[c] += __shfl_xor(acc[c], m, 64);
  }
  if (lane < 8) {
    int cb = lane * 8;
    float4 b0 = *(const float4*)&bias[cb];
    float4 b1 = *(const float4*)&bias[cb + 4];
    float4 o0 = make_float4(acc[0] + b0.x, acc[1] + b0.y, acc[2] + b0.z, acc[3] + b0.w);
    float4 o1 = make_float4(acc[4] + b1.x, acc[5] + b1.y, acc[6] + b1.z, acc[7] + b1.w);
    *(float4*)&out[(size_t)n * 64 + cb] = o0;
    *(float4*)&out[(size_t)n * 64 + cb + 4] = o1;
  }
}

// ---------------- host launch ----------------

extern "C" void kernel_launch(void* const* d_in, const int* in_sizes, int n_in,
                              void* d_out, int out_size, void* d_ws, size_t ws_size,
                              hipStream_t stream) {
  const float* x   = (const float*)d_in[0];
  const int*   ei  = (const int*)d_in[1];
  const float* W1  = (const float*)d_in[2];
  const float* as1 = (const float*)d_in[3];
  const float* ad1 = (const float*)d_in[4];
  const float* b1  = (const float*)d_in[5];
  const float* W2  = (const float*)d_in[6];
  const float* as2 = (const float*)d_in[7];
  const float* ad2 = (const float*)d_in[8];
  const float* b2  = (const float*)d_in[9];
  const float* W3  = (const float*)d_in[10];
  const float* as3 = (const float*)d_in[11];
  const float* ad3 = (const float*)d_in[12];
  const float* b3  = (const float*)d_in[13];
  float* out = (float*)d_out;

  const int N  = in_sizes[0] / 128;
  const int E  = in_sizes[1] / 2;
  const int EP = E + N;

  char* p = (char*)d_ws;
  auto carve = [&](size_t bytes) -> void* {
    void* r = (void*)p;
    p += (bytes + 255) & ~size_t(255);
    return r;
  };
  int*      deg  = (int*)carve(size_t(N) * 4);
  int*      rowp = (int*)carve(size_t(N + 1) * 4);
  int*      cur  = (int*)carve(size_t(N) * 4);
  int*      part = (int*)carve(1024 * 4);
  int*      col  = (int*)carve(size_t(EP) * 4);
  float*    asrc = (float*)carve(size_t(N) * HEADS * 4);
  float*    adst = (float*)carve(size_t(N) * HEADS * 4);
  _Float16* Wt1  = (_Float16*)carve(128 * 128 * 2);
  _Float16* Wt2  = (_Float16*)carve(128 * 128 * 2);
  _Float16* Wt3  = (_Float16*)carve(256 * 128 * 2);
  _Float16* Hb   = (_Float16*)carve(size_t(N) * 256 * 2);  // gemm outputs
  _Float16* Ab   = (_Float16*)carve(size_t(N) * 128 * 2);  // aggregation outputs

  hipMemsetAsync(deg, 0, size_t(N) * 4, stream);
  hipMemsetAsync(cur, 0, size_t(N) * 4, stream);

  int gEP = (EP + 255) / 256;
  count_deg_kernel<<<gEP, 256, 0, stream>>>(ei, deg, E, N);
  int nb = (N + 1023) / 1024;
  scan_block_kernel<<<nb, 1024, 0, stream>>>(deg, rowp, part, N);
  scan_partials_kernel<<<1, 1024, 0, stream>>>(part, nb);
  add_off_kernel<<<(N + 256) / 256, 256, 0, stream>>>(rowp, part, N, EP);
  scatter_kernel<<<gEP, 256, 0, stream>>>(ei, rowp, cur, col, E, N);

  convert_wt3_kernel<<<dim3(128, 3), 256, 0, stream>>>(W1, Wt1, W2, Wt2, W3, Wt3);

  int gM = (N + 63) / 64;
  int gN4 = (N + 3) / 4;
  int gN2 = (N + 1) / 2;

  // layer 1 (A = x fp32 converted in-register; alpha fused into epilogue)
  gemm_mfma_kernel<1, 2><<<dim3(gM, 1), 256, 0, stream>>>(
      x, Wt1, as1, ad1, Hb, asrc, adst, N, 128);
  aggregate_concat_kernel<<<gN4, 256, 0, stream>>>(Hb, asrc, adst, b1, rowp, col, Ab, N);
  // layer 2
  gemm_mfma_kernel<0, 2><<<dim3(gM, 1), 256, 0, stream>>>(
      Ab, Wt2, as2, ad2, Hb, asrc, adst, N, 128);
  aggregate_concat_kernel<<<gN4, 256, 0, stream>>>(Hb, asrc, adst, b2, rowp, col, Ab, N);
  // layer 3 (Fout=256, C=64, two col-panels of 2 heads each; mean over heads)
  gemm_mfma_kernel<0, 4><<<dim3(gM, 2), 256, 0, stream>>>(
      Ab, Wt3, as3, ad3, Hb, asrc, adst, N, 256);
  aggregate_mean_kernel<<<gN2, 128, 0, stream>>>(Hb, asrc, adst, b3, rowp, col, out, N);
}